// Round 5
// baseline (41.021 us; speedup 1.0000x reference)
//
#include <hip/hip_runtime.h>

#define SURV_EPS 1e-7f
#define T_BINS 32
#define NBLOCKS 2048
#define NTHREADS 256

// Per-chunk contribution: -log(product of selected likelihood terms).
// jb = first bin index of this float4 chunk; tg = (duration, event).
__device__ __forceinline__ float chunk_nll(const float4 p, const int2 tg, const int jb)
{
    int t_i = tg.x;
    t_i = t_i < 1 ? 1 : (t_i > T_BINS ? T_BINS : t_i);
    const bool evb = (tg.y != 0);
    // used-bin window [lo, hi):  event: [t_i-1, T); censored: [0, t_i)
    const int lo = evb ? (t_i - 1) : 0;
    const int hi = evb ? T_BINS    : t_i;

    const float pv[4] = {p.x, p.y, p.z, p.w};
    float prod = 1.0f;
#pragma unroll
    for (int k = 0; k < 4; ++k) {
        const int j = jb + k;
        const float h = fminf(fmaxf(pv[k], SURV_EPS), 1.0f - SURV_EPS);
        const float x = evb ? h : (1.0f - h);   // both already in [eps, 1-eps]
        const bool use = (j >= lo) & (j < hi);
        prod *= use ? x : 1.0f;
    }
    return -__logf(prod);
}

// Kernel 1: grid-stride over float4 chunks, 2x unrolled with independent loads
// (doubles per-wave in-flight bytes; keeps perfect stride-16 coalescing).
// NOTE (round 3 post-mortem): do NOT fuse the final reduction via a last-block
// counter — 2048 agent-scope atomics on one line + per-block L2 wb/inv cost
// ~90 us on 8-XCD CDNA4. The second launch costs ~3 us. Two kernels win.
__global__ __launch_bounds__(NTHREADS) void surv_loss_partial(
    const float* __restrict__ preds,
    const int* __restrict__ targets,
    double* __restrict__ partial,
    int n_rows)
{
    const int n_chunks = n_rows * (T_BINS / 4);  // 8 chunks per row
    const int stride   = gridDim.x * blockDim.x;
    const float4* __restrict__ p4 = reinterpret_cast<const float4*>(preds);
    const int2*   __restrict__ t2 = reinterpret_cast<const int2*>(targets);

    double acc = 0.0;
    int i = blockIdx.x * blockDim.x + threadIdx.x;

    for (; i + stride < n_chunks; i += 2 * stride) {
        const int ia = i;
        const int ib = i + stride;
        // four independent loads issued before any dependent compute
        const float4 pa = p4[ia];
        const float4 pb = p4[ib];
        const int2   ta = t2[ia >> 3];
        const int2   tb = t2[ib >> 3];
        float s = chunk_nll(pa, ta, (ia & 7) << 2);
        s      += chunk_nll(pb, tb, (ib & 7) << 2);
        acc += (double)s;
    }
    if (i < n_chunks) {
        acc += (double)chunk_nll(p4[i], t2[i >> 3], (i & 7) << 2);
    }

    __shared__ double sm[NTHREADS];
    const int tid = threadIdx.x;
    sm[tid] = acc;
    __syncthreads();
#pragma unroll
    for (int sN = NTHREADS / 2; sN > 0; sN >>= 1) {
        if (tid < sN) sm[tid] += sm[tid + sN];
        __syncthreads();
    }
    if (tid == 0) partial[blockIdx.x] = sm[0];
}

// Kernel 2: single block reduces the per-block partials, writes mean as f32.
__global__ __launch_bounds__(NTHREADS) void surv_loss_finish(
    const double* __restrict__ partial,
    float* __restrict__ out,
    int n_partials,
    int n_rows)
{
    const int tid = threadIdx.x;
    double acc = 0.0;
    for (int i = tid; i < n_partials; i += NTHREADS) acc += partial[i];

    __shared__ double sm[NTHREADS];
    sm[tid] = acc;
    __syncthreads();
#pragma unroll
    for (int sN = NTHREADS / 2; sN > 0; sN >>= 1) {
        if (tid < sN) sm[tid] += sm[tid + sN];
        __syncthreads();
    }
    if (tid == 0) out[0] = (float)(sm[0] / (double)n_rows);
}

extern "C" void kernel_launch(void* const* d_in, const int* in_sizes, int n_in,
                              void* d_out, int out_size, void* d_ws, size_t ws_size,
                              hipStream_t stream) {
    const float* preds   = (const float*)d_in[0];
    const int*   targets = (const int*)d_in[1];
    const int n_rows = in_sizes[0] / T_BINS;   // 1,500,000

    double* partial = (double*)d_ws;           // NBLOCKS doubles = 16 KiB
    float*  out     = (float*)d_out;

    surv_loss_partial<<<NBLOCKS, NTHREADS, 0, stream>>>(preds, targets, partial, n_rows);
    surv_loss_finish<<<1, NTHREADS, 0, stream>>>(partial, out, NBLOCKS, n_rows);
}

// Round 6
// 38.855 us; speedup vs baseline: 1.0557x; 1.0557x over previous
//
#include <hip/hip_runtime.h>

#define SURV_EPS 1e-7f
#define T_BINS 32
#define NBLOCKS 2048
#define NTHREADS 256

// Kernel 1: grid-stride over float4 chunks of preds; per-block double partials.
// Tricks: (1) log-of-product -> one __logf per chunk; (2) window skip -> the
// float4 load is exec-masked off when the chunk's 4 bins don't intersect the
// row's used window (censored [0,t_i), event [t_i-1,32)) -- skipped chunks
// contribute exactly -log(1) = 0, and their 16B segments are never fetched.
// NOTE (round 3 post-mortem): do NOT fuse the final reduce via last-block
// counter -- 2048 agent-scope atomics + per-block L2 wb/inv cost ~90 us on
// 8-XCD CDNA4. NOTE (round 4): far-apart 2x unroll regressed; BW-bound.
__global__ __launch_bounds__(NTHREADS) void surv_loss_partial(
    const float* __restrict__ preds,
    const int* __restrict__ targets,
    double* __restrict__ partial,
    int n_rows)
{
    const int n_chunks = n_rows * (T_BINS / 4);  // 8 chunks per row
    const float4* __restrict__ p4 = reinterpret_cast<const float4*>(preds);
    const int2*   __restrict__ t2 = reinterpret_cast<const int2*>(targets);

    double acc = 0.0;

    for (int i = blockIdx.x * blockDim.x + threadIdx.x; i < n_chunks;
         i += gridDim.x * blockDim.x) {
        const int r  = i >> 3;        // row
        const int jb = (i & 7) << 2;  // first bin index of this chunk

        // 8 consecutive lanes share a row -> same cache line, L1 broadcast
        const int2 tg = t2[r];
        int t_i = tg.x;
        t_i = t_i < 1 ? 1 : (t_i > T_BINS ? T_BINS : t_i);
        const bool evb = (tg.y != 0);
        // used-bin window [lo, hi):  event: [t_i-1, T); censored: [0, t_i)
        const int lo = evb ? (t_i - 1) : 0;
        const int hi = evb ? T_BINS    : t_i;

        // Skip the load + math when [jb, jb+4) does not intersect [lo, hi).
        if ((jb + 4 > lo) & (jb < hi)) {
            const float4 p = p4[i];
            const float pv[4] = {p.x, p.y, p.z, p.w};
            float prod = 1.0f;
#pragma unroll
            for (int k = 0; k < 4; ++k) {
                const int j = jb + k;
                const float h = fminf(fmaxf(pv[k], SURV_EPS), 1.0f - SURV_EPS);
                const float x = evb ? h : (1.0f - h);  // both in [eps, 1-eps]
                const bool use = (j >= lo) & (j < hi);
                prod *= use ? x : 1.0f;
            }
            acc -= (double)__logf(prod);
        }
    }

    __shared__ double sm[NTHREADS];
    const int tid = threadIdx.x;
    sm[tid] = acc;
    __syncthreads();
#pragma unroll
    for (int sN = NTHREADS / 2; sN > 0; sN >>= 1) {
        if (tid < sN) sm[tid] += sm[tid + sN];
        __syncthreads();
    }
    if (tid == 0) partial[blockIdx.x] = sm[0];
}

// Kernel 2: single block reduces the per-block partials, writes mean as f32.
__global__ __launch_bounds__(NTHREADS) void surv_loss_finish(
    const double* __restrict__ partial,
    float* __restrict__ out,
    int n_partials,
    int n_rows)
{
    const int tid = threadIdx.x;
    double acc = 0.0;
    for (int i = tid; i < n_partials; i += NTHREADS) acc += partial[i];

    __shared__ double sm[NTHREADS];
    sm[tid] = acc;
    __syncthreads();
#pragma unroll
    for (int sN = NTHREADS / 2; sN > 0; sN >>= 1) {
        if (tid < sN) sm[tid] += sm[tid + sN];
        __syncthreads();
    }
    if (tid == 0) out[0] = (float)(sm[0] / (double)n_rows);
}

extern "C" void kernel_launch(void* const* d_in, const int* in_sizes, int n_in,
                              void* d_out, int out_size, void* d_ws, size_t ws_size,
                              hipStream_t stream) {
    const float* preds   = (const float*)d_in[0];
    const int*   targets = (const int*)d_in[1];
    const int n_rows = in_sizes[0] / T_BINS;   // 1,500,000

    double* partial = (double*)d_ws;           // NBLOCKS doubles = 16 KiB
    float*  out     = (float*)d_out;

    surv_loss_partial<<<NBLOCKS, NTHREADS, 0, stream>>>(preds, targets, partial, n_rows);
    surv_loss_finish<<<1, NTHREADS, 0, stream>>>(partial, out, NBLOCKS, n_rows);
}